// Round 17
// baseline (445.184 us; speedup 1.0000x reference)
//
#include <hip/hip_runtime.h>
#include <hip/hip_bf16.h>
#include <math.h>

#define NB   16
#define NTOK 577
#define CDIM 768
#define NH   12
#define HID  3072
#define RTOT (NB*NTOK)        // 9232
#define RPAD (((RTOT+127)/128)*128) // 9344
#define BH   (NB*NH)          // 192
#define QT   40               // 640/16 fragment-tiles per (b,h)
#define KF_C (CDIM/32)        // 24

typedef __attribute__((ext_vector_type(8))) short bf16x8;
typedef __attribute__((ext_vector_type(4))) float f32x4;
typedef unsigned short u16;

__device__ inline void load_lds16(const void* g, void* l) {
    __builtin_amdgcn_global_load_lds(
        (const __attribute__((address_space(1))) unsigned*)g,
        (__attribute__((address_space(3))) unsigned*)l, 16, 0, 0);
}

// fragment-blob address for element (m, c) of an [M][C] bf16 matrix packed in
// MFMA A-operand order: blob(mt, kf) is 512 u16, lane(fq*16+fr) holds 8 elems.
__device__ inline size_t blobA(int m, int c, int Kf) {
    return ((size_t)(m >> 4) * Kf + (c >> 5)) * 512 +
           (((c >> 3) & 3) * 16 + (m & 15)) * 8 + (c & 7);
}

// exp-based tanh gelu
__device__ inline float fast_gelu(float x) {
    float y = 0.7978845608f * (x + 0.044715f * x * x * x);
    float e = __expf(2.0f * y);
    float th = 1.0f - 2.0f / (e + 1.0f);
    return 0.5f * x * (1.0f + th);
}

// ---------------------------------------------------------------------------
// Weight fp32 [K][N] -> bf16 fragment blobs (B-operand: roles m->n, c->k).
// ---------------------------------------------------------------------------
__global__ __launch_bounds__(256) void wconvert_blob(
    const float* __restrict__ src, u16* __restrict__ dst, int K, int N)
{
    int n  = blockIdx.x * 256 + threadIdx.x;
    int kp = blockIdx.y;                     // k-chunk of 8
    const float* s = src + (size_t)(kp * 8) * N + n;
    __hip_bfloat16 h0 = __float2bfloat16(s[0 * N]);
    __hip_bfloat16 h1 = __float2bfloat16(s[1 * N]);
    __hip_bfloat16 h2 = __float2bfloat16(s[2 * N]);
    __hip_bfloat16 h3 = __float2bfloat16(s[3 * N]);
    __hip_bfloat16 h4 = __float2bfloat16(s[4 * N]);
    __hip_bfloat16 h5 = __float2bfloat16(s[5 * N]);
    __hip_bfloat16 h6 = __float2bfloat16(s[6 * N]);
    __hip_bfloat16 h7 = __float2bfloat16(s[7 * N]);
    ushort4 a = make_ushort4(*(u16*)&h0, *(u16*)&h1, *(u16*)&h2, *(u16*)&h3);
    ushort4 b = make_ushort4(*(u16*)&h4, *(u16*)&h5, *(u16*)&h6, *(u16*)&h7);
    u16* d = dst + ((size_t)(n >> 4) * (K >> 5) + (kp >> 2)) * 512 +
             ((kp & 3) * 16 + (n & 15)) * 8;
    *(ushort4*)(d)     = a;
    *(ushort4*)(d + 4) = b;
}

// ---------------------------------------------------------------------------
// LayerNorm -> bf16 fragment blob (Kf = 24). Values staged in an LDS row
// buffer, then written as blob-contiguous 16B stores.
// ---------------------------------------------------------------------------
__global__ __launch_bounds__(256) void ln_kernel(
    const float* __restrict__ x, const float* __restrict__ g,
    const float* __restrict__ b, u16* __restrict__ out)
{
    int row = blockIdx.x;
    const float* xr = x + (size_t)row * CDIM;
    int t = threadIdx.x;
    float v0 = xr[t], v1 = xr[t + 256], v2 = xr[t + 512];
    float s  = v0 + v1 + v2;
    float s2 = v0*v0 + v1*v1 + v2*v2;
    #pragma unroll
    for (int off = 32; off; off >>= 1) {
        s  += __shfl_xor(s, off);
        s2 += __shfl_xor(s2, off);
    }
    __shared__ float red[10];
    __shared__ __align__(16) u16 rowbuf[CDIM];
    int wave = t >> 6, lane = t & 63;
    if (lane == 0) { red[wave] = s; red[wave + 4] = s2; }
    __syncthreads();
    if (t == 0) {
        float ts  = red[0] + red[1] + red[2] + red[3];
        float ts2 = red[4] + red[5] + red[6] + red[7];
        float mu  = ts * (1.0f / CDIM);
        float var = ts2 * (1.0f / CDIM) - mu * mu;
        red[8] = mu;
        red[9] = rsqrtf(var + 1e-5f);
    }
    __syncthreads();
    float mu = red[8], rs = red[9];
    #pragma unroll
    for (int i = 0; i < 3; ++i) {
        int c = t + i * 256;
        float v = (i == 0 ? v0 : (i == 1 ? v1 : v2));
        __hip_bfloat16 hb = __float2bfloat16((v - mu) * rs * g[c] + b[c]);
        rowbuf[c] = *(u16*)&hb;
    }
    __syncthreads();
    if (t < CDIM / 8) {
        int c0 = t * 8;
        *(bf16x8*)(out + blobA(row, c0, KF_C)) = *(const bf16x8*)(rowbuf + c0);
    }
}

// ---------------------------------------------------------------------------
// LDS-staged 4-wave GEMM (m97 structure) with XCD-slab swizzle, BK = 32.
// KFV (= K/32) is a TEMPLATE CONSTANT; K-loop unrolled in chunks of 8 with
// compile-time buffer parity (R16: fc1 79.4 -> 72.5, VALUBusy 45 -> 40).
// Tiles: <4,8> = 64x128 (qkv/fc1: large grids); <4,4> = 64x64 (proj/fc2:
// doubles their 870-block grids to 1740 = 6.8 blocks/CU — R16 showed fc2 at
// Occupancy 30%, VALUBusy 15%: grid-starved + HBM-latency-bound).
// Block ordering within an XCD (xcd = fid&7 picks the m-slab residue):
//   default (n-inner): A-panel hot; FLAGS&16 (m-inner): B-strip hot, XCD's
//   A-panels L2-resident (R12: FETCH halved for qkv/fc1).
// FLAGS: 1=gelu, 4=blob out, 8=qkv scatter, 16=m-inner, else fp32 out (+res).
// Requires KFV % 8 == 0 (24, 96: ok) and (MBL+NBL) % 4 == 0.
// ---------------------------------------------------------------------------
template<int MBL, int NBL, int FLAGS, int KFV>
__global__ __launch_bounds__(256) void tile_gemm(
    const u16* __restrict__ Ab, const u16* __restrict__ Bb,
    const float* __restrict__ bias, const float* __restrict__ res,
    void* __restrict__ outv,
    u16* __restrict__ Qp, u16* __restrict__ Kp, u16* __restrict__ Vp,
    int M, int Nc, int nb, int mtiles)
{
    constexpr int NST  = (MBL + NBL) / 4;   // DMA blobs per wave per step
    constexpr int BUFU = (MBL + NBL) * 512; // u16 per buffer
    constexpr int MH2  = MBL / 2, NW2 = NBL / 2;
    constexpr size_t tstr = (size_t)KFV * 512;
    __shared__ __align__(16) u16 smem[2 * BUFU];

    int tid = threadIdx.x, lane = tid & 63, wv = tid >> 6;
    int fr = lane & 15, fq = lane >> 4;
    int wm = wv >> 1, wn = wv & 1;

    int fid = blockIdx.x;
    int xcd = fid & 7, w = fid >> 3;
    int slab, n;
    if constexpr ((FLAGS & 16) != 0) {
        int nslab = (mtiles + 7) >> 3;
        n = w / nslab; slab = w - n * nslab;   // m-inner (slab varies fastest)
    } else {
        slab = w / nb; n = w - slab * nb;      // n-inner
    }
    int mtile = slab * 8 + xcd;
    if (mtile >= mtiles) return;
    int m0 = mtile * (MBL * 16), n0 = n * (NBL * 16);

    // staging pointers: blob bi = wv + i*4; [0,MBL)=A-blobs, rest B-blobs
    const u16* gp[NST];
    u16* ldst[NST];
    #pragma unroll
    for (int i = 0; i < NST; ++i) {
        int bi = wv + i * 4;
        gp[i] = (bi < MBL)
            ? Ab + ((size_t)(m0 >> 4) + bi) * tstr + lane * 8
            : Bb + ((size_t)(n0 >> 4) + (bi - MBL)) * tstr + lane * 8;
        ldst[i] = smem + bi * 512;
    }

    f32x4 acc[MH2][NW2];
    #pragma unroll
    for (int mi = 0; mi < MH2; ++mi)
        #pragma unroll
        for (int ni = 0; ni < NW2; ++ni) acc[mi][ni] = (f32x4){0.f, 0.f, 0.f, 0.f};

    #pragma unroll
    for (int i = 0; i < NST; ++i) load_lds16(gp[i], ldst[i]);
    __syncthreads();

    for (int tb = 0; tb < KFV; tb += 8) {
        #pragma unroll
        for (int u = 0; u < 8; ++u) {
            int t = tb + u;
            // tb is a multiple of 8 -> parity of t is parity of u: compile-time
            constexpr int par[8] = {0, 1, 0, 1, 0, 1, 0, 1};
            int cur = par[u] * BUFU, nxt = par[(u + 1) & 7] * BUFU;
            if (t + 1 < KFV) {
                #pragma unroll
                for (int i = 0; i < NST; ++i)
                    load_lds16(gp[i] + (size_t)(t + 1) * 512, ldst[i] + nxt);
            }
            bf16x8 a[MH2], bfr[NW2];
            #pragma unroll
            for (int mi = 0; mi < MH2; ++mi)
                a[mi] = *(const bf16x8*)(smem + cur + (wm * MH2 + mi) * 512 + lane * 8);
            #pragma unroll
            for (int ni = 0; ni < NW2; ++ni)
                bfr[ni] = *(const bf16x8*)(smem + cur + (MBL + wn * NW2 + ni) * 512 + lane * 8);
            #pragma unroll
            for (int mi = 0; mi < MH2; ++mi)
                #pragma unroll
                for (int ni = 0; ni < NW2; ++ni)
                    acc[mi][ni] = __builtin_amdgcn_mfma_f32_16x16x32_bf16(
                        a[mi], bfr[ni], acc[mi][ni], 0, 0, 0);
            __syncthreads();
        }
    }

    int m0w = m0 + wm * (MH2 * 16);
    int n0w = n0 + wn * (NW2 * 16);
    float* outf = (float*)outv;
    u16* outblob = (u16*)outv;

    if constexpr ((FLAGS & 8) != 0) {
        // qkv scatter: wave's 64-col span is one (sec, head), uniform per wave
        int sec = n0w / CDIM;
        int h   = (n0w % CDIM) / 64;
        #pragma unroll
        for (int mi = 0; mi < MH2; ++mi) {
            #pragma unroll
            for (int rg = 0; rg < 4; ++rg) {
                int gm = m0w + mi * 16 + fq * 4 + rg;
                if (gm >= M) continue;
                int b   = gm / NTOK;
                int row = gm - b * NTOK;
                int bh  = b * NH + h;
                #pragma unroll
                for (int ni = 0; ni < NW2; ++ni) {
                    int d = ni * 16 + fr;
                    float v = acc[mi][ni][rg] + bias[n0w + d];
                    __hip_bfloat16 hb = __float2bfloat16(v);
                    if (sec == 0) {
                        Qp[(size_t)(bh * QT + (row >> 4)) * 1024 + (d >> 5) * 512 +
                           (((d >> 3) & 3) * 16 + (row & 15)) * 8 + (d & 7)] = *(u16*)&hb;
                    } else if (sec == 1) {
                        Kp[(size_t)(bh * QT + (row >> 4)) * 1024 + (d >> 5) * 512 +
                           (((d >> 3) & 3) * 16 + (row & 15)) * 8 + (d & 7)] = *(u16*)&hb;
                    } else {
                        Vp[((size_t)(bh * 4 + (d >> 4)) * 20 + (row >> 5)) * 512 +
                           (((row >> 3) & 3) * 16 + (d & 15)) * 8 + (row & 7)] = *(u16*)&hb;
                    }
                }
            }
        }
        return;
    }

    if constexpr ((FLAGS & 4) != 0) {
        // blob out: per-wave private LDS staging per m-blob (wave-sync:
        // same wave writes then reads, program order), then linear 16B stores.
        u16* sb = smem + wv * 1024;
        int KfO = Nc >> 5;
        #pragma unroll
        for (int mi = 0; mi < MH2; ++mi) {
            #pragma unroll
            for (int ni = 0; ni < NW2; ++ni)
                #pragma unroll
                for (int rg = 0; rg < 4; ++rg) {
                    int cl = ni * 16 + fr;
                    float v = acc[mi][ni][rg] + bias[n0w + cl];
                    if (FLAGS & 1) v = fast_gelu(v);
                    __hip_bfloat16 hb = __float2bfloat16(v);
                    sb[(cl >> 5) * 512 +
                       (((cl >> 3) & 3) * 16 + fq * 4 + rg) * 8 + (cl & 7)] = *(u16*)&hb;
                }
            u16* dst = outblob + ((size_t)((m0w >> 4) + mi) * KfO + (n0w >> 5)) * 512;
            *(bf16x8*)(dst + lane * 16)     = *(const bf16x8*)(sb + lane * 16);
            *(bf16x8*)(dst + lane * 16 + 8) = *(const bf16x8*)(sb + lane * 16 + 8);
        }
        return;
    }

    #pragma unroll
    for (int mi = 0; mi < MH2; ++mi) {
        #pragma unroll
        for (int rg = 0; rg < 4; ++rg) {
            int gm = m0w + mi * 16 + fq * 4 + rg;
            if (gm >= M) continue;
            #pragma unroll
            for (int ni = 0; ni < NW2; ++ni) {
                int gn = n0w + ni * 16 + fr;
                float v = acc[mi][ni][rg] + bias[gn];
                if (res) v += res[(size_t)gm * Nc + gn];
                outf[(size_t)gm * Nc + gn] = v;
            }
        }
    }
}

// ---------------------------------------------------------------------------
// MFMA flash attention, SWAPPED QK^T (in-register softmax rows) — R9-proven.
// XCD-swizzled grid (xcd owns 24 heads, qc-inner: K/V L2-hot, FETCH at
// compulsory). Double-buffered K/V staging. setprio on MFMA clusters.
// ---------------------------------------------------------------------------
__global__ __launch_bounds__(256) void attn_mfma(
    const u16* __restrict__ Qp, const u16* __restrict__ Kp,
    const u16* __restrict__ Vp, u16* __restrict__ outp)
{
    __shared__ __align__(16) u16 Ks[2][4096];
    __shared__ __align__(16) u16 Vs[2][4096];
    __shared__ __align__(16) u16 Ps[4 * 16 * 72];

    int fid = blockIdx.x;
    int xcd = fid & 7, w = fid >> 3;       // w in [0, 240)
    int bhl = w / 10, qc = w - bhl * 10;   // qc-inner
    int bh = xcd * 24 + bhl;
    int b = bh / NH, h = bh % NH;
    int t = threadIdx.x, lane = t & 63, wv = t >> 6;
    int fr = lane & 15, fq = lane >> 4;

    int mt = qc * 4 + wv;
    const u16* qbase = Qp + (size_t)(bh * QT + mt) * 1024 + lane * 8;
    bf16x8 qf0 = *(const bf16x8*)(qbase);
    bf16x8 qf1 = *(const bf16x8*)(qbase + 512);

    const u16* kg = Kp + (size_t)bh * (QT * 1024) + wv * 1024 + lane * 8;
    const u16* vg = Vp + ((size_t)(bh * 4 + wv) * 20) * 512 + lane * 8;
    u16* psw = Ps + wv * (16 * 72);

#define STAGE(buf, kt) do {                                        \
    load_lds16(kg + (kt) * 4096,       &Ks[buf][wv * 1024]);       \
    load_lds16(kg + (kt) * 4096 + 512, &Ks[buf][wv * 1024 + 512]); \
    load_lds16(vg + (kt) * 1024,       &Vs[buf][wv * 1024]);       \
    load_lds16(vg + (kt) * 1024 + 512, &Vs[buf][wv * 1024 + 512]); \
} while (0)

    f32x4 o[4];
    #pragma unroll
    for (int i = 0; i < 4; ++i) o[i] = (f32x4){0.f, 0.f, 0.f, 0.f};
    float m_r = -1e30f, l_r = 0.f;   // per-lane state for q = fr

    STAGE(0, 0);
    __syncthreads();

    for (int kt = 0; kt < 10; ++kt) {
        int cur = kt & 1;
        if (kt + 1 < 10) STAGE(cur ^ 1, kt + 1);

        f32x4 sc[4];
        __builtin_amdgcn_s_setprio(1);
        #pragma unroll
        for (int nt = 0; nt < 4; ++nt) {
            sc[nt] = (f32x4){0.f, 0.f, 0.f, 0.f};
            bf16x8 kf0 = *(const bf16x8*)(&Ks[cur][(nt * 2 + 0) * 512] + lane * 8);
            bf16x8 kf1 = *(const bf16x8*)(&Ks[cur][(nt * 2 + 1) * 512] + lane * 8);
            // SWAPPED: A = K (keys = rows), B = Q (q = cols) -> S^T
            sc[nt] = __builtin_amdgcn_mfma_f32_16x16x32_bf16(kf0, qf0, sc[nt], 0, 0, 0);
            sc[nt] = __builtin_amdgcn_mfma_f32_16x16x32_bf16(kf1, qf1, sc[nt], 0, 0, 0);
        }
        __builtin_amdgcn_s_setprio(0);

        int j0 = kt * 64;
        float p[4][4];
        #pragma unroll
        for (int nt = 0; nt < 4; ++nt)
            #pragma unroll
            for (int rg = 0; rg < 4; ++rg) {
                int k = j0 + nt * 16 + fq * 4 + rg;
                p[nt][rg] = (k < NTOK) ? sc[nt][rg] * 0.125f : -1e30f;
            }
        // in-register max tree over the lane's 16 scores
        float mx01 = fmaxf(fmaxf(p[0][0], p[0][1]), fmaxf(p[0][2], p[0][3]));
        float mx23 = fmaxf(fmaxf(p[1][0], p[1][1]), fmaxf(p[1][2], p[1][3]));
        float mx45 = fmaxf(fmaxf(p[2][0], p[2][1]), fmaxf(p[2][2], p[2][3]));
        float mx67 = fmaxf(fmaxf(p[3][0], p[3][1]), fmaxf(p[3][2], p[3][3]));
        float pm = fmaxf(fmaxf(mx01, mx23), fmaxf(mx45, mx67));
        // combine the 4 fq replicas of this q (lanes fr, fr+16, fr+32, fr+48)
        pm = fmaxf(pm, __shfl_xor(pm, 16));
        pm = fmaxf(pm, __shfl_xor(pm, 32));

        float mn = fmaxf(m_r, pm);
        float alpha = __expf(m_r - mn);
        m_r = mn;

        float rs = 0.f;
        #pragma unroll
        for (int nt = 0; nt < 4; ++nt)
            #pragma unroll
            for (int rg = 0; rg < 4; ++rg) {
                float pv = __expf(p[nt][rg] - mn);
                p[nt][rg] = pv;
                rs += pv;
            }
        rs += __shfl_xor(rs, 16);
        rs += __shfl_xor(rs, 32);
        l_r = l_r * alpha + rs;

        // P -> psw: lane owns row q=fr, 4 consecutive keys per nt -> b64 store
        #pragma unroll
        for (int nt = 0; nt < 4; ++nt) {
            __hip_bfloat16 c0 = __float2bfloat16(p[nt][0]);
            __hip_bfloat16 c1 = __float2bfloat16(p[nt][1]);
            __hip_bfloat16 c2 = __float2bfloat16(p[nt][2]);
            __hip_bfloat16 c3 = __float2bfloat16(p[nt][3]);
            ushort4 pk = make_ushort4(*(u16*)&c0, *(u16*)&c1, *(u16*)&c2, *(u16*)&c3);
            *(ushort4*)(psw + fr * 72 + nt * 16 + fq * 4) = pk;
        }

        // rescale O: its rows are q = fq*4+rg -> fetch those lanes' alpha
        #pragma unroll
        for (int rg = 0; rg < 4; ++rg) {
            float al = __shfl(alpha, fq * 4 + rg);
            #pragma unroll
            for (int dt = 0; dt < 4; ++dt)
                o[dt][rg] *= al;
        }

        bf16x8 pf0 = *(const bf16x8*)(psw + fr * 72 + fq * 8);
        bf16x8 pf1 = *(const bf16x8*)(psw + fr * 72 + 32 + fq * 8);
        __builtin_amdgcn_s_setprio(1);
        #pragma unroll
        for (int dt = 0; dt < 4; ++dt) {
            bf16x8 bv0 = *(const bf16x8*)(&Vs[cur][(dt * 2 + 0) * 512] + lane * 8);
            bf16x8 bv1 = *(const bf16x8*)(&Vs[cur][(dt * 2 + 1) * 512] + lane * 8);
            o[dt] = __builtin_amdgcn_mfma_f32_16x16x32_bf16(pf0, bv0, o[dt], 0, 0, 0);
            o[dt] = __builtin_amdgcn_mfma_f32_16x16x32_bf16(pf1, bv1, o[dt], 0, 0, 0);
        }
        __builtin_amdgcn_s_setprio(0);
        __syncthreads();   // drains this step's prefetch + read-sync of cur
    }
#undef STAGE

    #pragma unroll
    for (int rg = 0; rg < 4; ++rg) {
        int row = qc * 64 + wv * 16 + fq * 4 + rg;
        if (row < NTOK) {
            float lq = __shfl(l_r, fq * 4 + rg);   // l for O's q-row
            float rl = 1.0f / lq;
            int grow = b * NTOK + row;
            #pragma unroll
            for (int dt = 0; dt < 4; ++dt) {
                __hip_bfloat16 hb = __float2bfloat16(o[dt][rg] * rl);
                outp[blobA(grow, h * 64 + dt * 16 + fr, KF_C)] = *(u16*)&hb;
            }
        }
    }
}

// ---------------------------------------------------------------------------
static inline int tg_grid(int nb, int mt) { return 8 * nb * ((mt + 7) / 8); }

extern "C" void kernel_launch(void* const* d_in, const int* in_sizes, int n_in,
                              void* d_out, int out_size, void* d_ws, size_t ws_size,
                              hipStream_t stream)
{
    const float* x      = (const float*)d_in[0];
    const float* ln1_g  = (const float*)d_in[1];
    const float* ln1_b  = (const float*)d_in[2];
    const float* w_qkv  = (const float*)d_in[3];
    const float* b_qkv  = (const float*)d_in[4];
    const float* w_proj = (const float*)d_in[5];
    const float* b_proj = (const float*)d_in[6];
    const float* ln2_g  = (const float*)d_in[7];
    const float* ln2_b  = (const float*)d_in[8];
    const float* w_fc1  = (const float*)d_in[9];
    const float* b_fc1  = (const float*)d_in[10];
    const float* w_fc2  = (const float*)d_in[11];
    const float* b_fc2  = (const float*)d_in[12];
    float* out = (float*)d_out;

    char* w = (char*)d_ws;
    u16* Bqkv = (u16*)w; w += (size_t)3*CDIM*CDIM*2;
    u16* Bproj= (u16*)w; w += (size_t)CDIM*CDIM*2;
    u16* Bfc1 = (u16*)w; w += (size_t)HID*CDIM*2;
    u16* Bfc2 = (u16*)w; w += (size_t)CDIM*HID*2;
    u16* hA   = (u16*)w; w += (size_t)RPAD*CDIM*2;   // blob activations (768)
    u16* h3A  = (u16*)w; w += (size_t)RPAD*HID*2;    // blob activations (3072)
    u16* Qp   = (u16*)w; w += (size_t)BH*QT*1024*2;
    u16* Kp   = (u16*)w; w += (size_t)BH*QT*1024*2;
    u16* Vp   = (u16*)w; w += (size_t)BH*4*20*512*2;

    int mt64 = (RTOT + 63) / 64;     // 145 m-tiles for 64-row blocks

    // 0. weights -> fragment blobs
    wconvert_blob<<<dim3(3*CDIM/256, CDIM/8), 256, 0, stream>>>(w_qkv,  Bqkv, CDIM, 3*CDIM);
    wconvert_blob<<<dim3(CDIM/256,   CDIM/8), 256, 0, stream>>>(w_proj, Bproj, CDIM, CDIM);
    wconvert_blob<<<dim3(HID/256,    CDIM/8), 256, 0, stream>>>(w_fc1,  Bfc1, CDIM, HID);
    wconvert_blob<<<dim3(CDIM/256,   HID/8),  256, 0, stream>>>(w_fc2,  Bfc2, HID, CDIM);

    // 1. hA = LN1(x)  (blob)
    ln_kernel<<<RTOT, 256, 0, stream>>>(x, ln1_g, ln1_b, hA);
    // 2. qkv GEMM -> Q/K/V blobs  (64x128, m-inner, Kf=24)
    tile_gemm<4, 8, 8 | 16, 24><<<tg_grid(3*CDIM/128, mt64), 256, 0, stream>>>(
        hA, Bqkv, b_qkv, nullptr, nullptr, Qp, Kp, Vp,
        RTOT, 3*CDIM, 3*CDIM/128, mt64);
    // 3. attention -> hA (blob)
    attn_mfma<<<8 * 24 * 10, 256, 0, stream>>>(Qp, Kp, Vp, hA);
    // 4. x1 = x + hA @ Bproj^T + b_proj -> d_out (fp32; 64x64, m-inner, Kf=24:
    //    grid 12x145 = 1740 blocks, 6.8/CU — fixes proj's 3.4/CU starvation)
    tile_gemm<4, 4, 0 | 16, 24><<<tg_grid(CDIM/64, mt64), 256, 0, stream>>>(
        hA, Bproj, b_proj, x, out, nullptr, nullptr, nullptr,
        RTOT, CDIM, CDIM/64, mt64);
    // 5. hA = LN2(x1)  (blob)
    ln_kernel<<<RTOT, 256, 0, stream>>>(out, ln2_g, ln2_b, hA);
    // 6. h3A = gelu(hA @ Bfc1^T + b_fc1)  (blob out; 64x128, m-inner, Kf=24)
    tile_gemm<4, 8, 5 | 16, 24><<<tg_grid(HID/128, mt64), 256, 0, stream>>>(
        hA, Bfc1, b_fc1, nullptr, h3A, nullptr, nullptr, nullptr,
        RTOT, HID, HID/128, mt64);
    // 7. out = x1 + h3A @ Bfc2^T + b_fc2  (fp32; 64x64, m-inner, Kf=96:
    //    1740 blocks, B-strip 393KB hot per XCD, A streams at compulsory)
    tile_gemm<4, 4, 0 | 16, 96><<<tg_grid(CDIM/64, mt64), 256, 0, stream>>>(
        h3A, Bfc2, b_fc2, out, out, nullptr, nullptr, nullptr,
        RTOT, CDIM, CDIM/64, mt64);
}

// Round 18
// 426.638 us; speedup vs baseline: 1.0435x; 1.0435x over previous
//
#include <hip/hip_runtime.h>
#include <hip/hip_bf16.h>
#include <math.h>

#define NB   16
#define NTOK 577
#define CDIM 768
#define NH   12
#define HID  3072
#define RTOT (NB*NTOK)        // 9232
#define RPAD (((RTOT+127)/128)*128) // 9344
#define BH   (NB*NH)          // 192
#define QT   40               // 640/16 fragment-tiles per (b,h)
#define KF_C (CDIM/32)        // 24

typedef __attribute__((ext_vector_type(8))) short bf16x8;
typedef __attribute__((ext_vector_type(4))) float f32x4;
typedef unsigned short u16;

__device__ inline void load_lds16(const void* g, void* l) {
    __builtin_amdgcn_global_load_lds(
        (const __attribute__((address_space(1))) unsigned*)g,
        (__attribute__((address_space(3))) unsigned*)l, 16, 0, 0);
}

// fragment-blob address for element (m, c) of an [M][C] bf16 matrix packed in
// MFMA A-operand order: blob(mt, kf) is 512 u16, lane(fq*16+fr) holds 8 elems.
__device__ inline size_t blobA(int m, int c, int Kf) {
    return ((size_t)(m >> 4) * Kf + (c >> 5)) * 512 +
           (((c >> 3) & 3) * 16 + (m & 15)) * 8 + (c & 7);
}

// exp-based tanh gelu
__device__ inline float fast_gelu(float x) {
    float y = 0.7978845608f * (x + 0.044715f * x * x * x);
    float e = __expf(2.0f * y);
    float th = 1.0f - 2.0f / (e + 1.0f);
    return 0.5f * x * (1.0f + th);
}

// ---------------------------------------------------------------------------
// Weight fp32 [K][N] -> bf16 fragment blobs (B-operand: roles m->n, c->k).
// ---------------------------------------------------------------------------
__global__ __launch_bounds__(256) void wconvert_blob(
    const float* __restrict__ src, u16* __restrict__ dst, int K, int N)
{
    int n  = blockIdx.x * 256 + threadIdx.x;
    int kp = blockIdx.y;                     // k-chunk of 8
    const float* s = src + (size_t)(kp * 8) * N + n;
    __hip_bfloat16 h0 = __float2bfloat16(s[0 * N]);
    __hip_bfloat16 h1 = __float2bfloat16(s[1 * N]);
    __hip_bfloat16 h2 = __float2bfloat16(s[2 * N]);
    __hip_bfloat16 h3 = __float2bfloat16(s[3 * N]);
    __hip_bfloat16 h4 = __float2bfloat16(s[4 * N]);
    __hip_bfloat16 h5 = __float2bfloat16(s[5 * N]);
    __hip_bfloat16 h6 = __float2bfloat16(s[6 * N]);
    __hip_bfloat16 h7 = __float2bfloat16(s[7 * N]);
    ushort4 a = make_ushort4(*(u16*)&h0, *(u16*)&h1, *(u16*)&h2, *(u16*)&h3);
    ushort4 b = make_ushort4(*(u16*)&h4, *(u16*)&h5, *(u16*)&h6, *(u16*)&h7);
    u16* d = dst + ((size_t)(n >> 4) * (K >> 5) + (kp >> 2)) * 512 +
             ((kp & 3) * 16 + (n & 15)) * 8;
    *(ushort4*)(d)     = a;
    *(ushort4*)(d + 4) = b;
}

// ---------------------------------------------------------------------------
// LayerNorm -> bf16 fragment blob (Kf = 24). Values staged in an LDS row
// buffer, then written as blob-contiguous 16B stores.
// ---------------------------------------------------------------------------
__global__ __launch_bounds__(256) void ln_kernel(
    const float* __restrict__ x, const float* __restrict__ g,
    const float* __restrict__ b, u16* __restrict__ out)
{
    int row = blockIdx.x;
    const float* xr = x + (size_t)row * CDIM;
    int t = threadIdx.x;
    float v0 = xr[t], v1 = xr[t + 256], v2 = xr[t + 512];
    float s  = v0 + v1 + v2;
    float s2 = v0*v0 + v1*v1 + v2*v2;
    #pragma unroll
    for (int off = 32; off; off >>= 1) {
        s  += __shfl_xor(s, off);
        s2 += __shfl_xor(s2, off);
    }
    __shared__ float red[10];
    __shared__ __align__(16) u16 rowbuf[CDIM];
    int wave = t >> 6, lane = t & 63;
    if (lane == 0) { red[wave] = s; red[wave + 4] = s2; }
    __syncthreads();
    if (t == 0) {
        float ts  = red[0] + red[1] + red[2] + red[3];
        float ts2 = red[4] + red[5] + red[6] + red[7];
        float mu  = ts * (1.0f / CDIM);
        float var = ts2 * (1.0f / CDIM) - mu * mu;
        red[8] = mu;
        red[9] = rsqrtf(var + 1e-5f);
    }
    __syncthreads();
    float mu = red[8], rs = red[9];
    #pragma unroll
    for (int i = 0; i < 3; ++i) {
        int c = t + i * 256;
        float v = (i == 0 ? v0 : (i == 1 ? v1 : v2));
        __hip_bfloat16 hb = __float2bfloat16((v - mu) * rs * g[c] + b[c]);
        rowbuf[c] = *(u16*)&hb;
    }
    __syncthreads();
    if (t < CDIM / 8) {
        int c0 = t * 8;
        *(bf16x8*)(out + blobA(row, c0, KF_C)) = *(const bf16x8*)(rowbuf + c0);
    }
}

// ---------------------------------------------------------------------------
// LDS-staged 4-wave GEMM (m97 structure) with XCD-slab swizzle, BK = 32.
// KFV (= K/32) is a TEMPLATE CONSTANT; K-loop unrolled in chunks of 8 with
// compile-time buffer parity (R16: fc1 79.4 -> 72.5, VALUBusy 45 -> 40).
// All GEMMs <4,8> = 64x128, LDS 24KB -> 6 blocks/CU (R13: BK=64 regressed;
// R17: <4,4> small-tile regressed — per-step overhead per MFMA doubled).
// Block ordering within an XCD (xcd = fid&7 picks the m-slab residue):
//   default (n-inner): A-panel hot (proj/fc2); FLAGS&16 (m-inner): B-strip
//   hot, XCD's A-panels L2-resident (qkv/fc1 — R12: FETCH halved).
// FLAGS: 1=gelu, 4=blob out, 8=qkv scatter, 16=m-inner, else fp32 out (+res).
// Requires KFV % 8 == 0 (24, 96: ok).
// ---------------------------------------------------------------------------
template<int MBL, int NBL, int FLAGS, int KFV>
__global__ __launch_bounds__(256) void tile_gemm(
    const u16* __restrict__ Ab, const u16* __restrict__ Bb,
    const float* __restrict__ bias, const float* __restrict__ res,
    void* __restrict__ outv,
    u16* __restrict__ Qp, u16* __restrict__ Kp, u16* __restrict__ Vp,
    int M, int Nc, int nb, int mtiles)
{
    constexpr int NST  = (MBL + NBL) / 4;   // DMA blobs per wave per step
    constexpr int BUFU = (MBL + NBL) * 512; // u16 per buffer
    constexpr int MH2  = MBL / 2, NW2 = NBL / 2;
    constexpr size_t tstr = (size_t)KFV * 512;
    __shared__ __align__(16) u16 smem[2 * BUFU];

    int tid = threadIdx.x, lane = tid & 63, wv = tid >> 6;
    int fr = lane & 15, fq = lane >> 4;
    int wm = wv >> 1, wn = wv & 1;

    int fid = blockIdx.x;
    int xcd = fid & 7, w = fid >> 3;
    int slab, n;
    if constexpr ((FLAGS & 16) != 0) {
        int nslab = (mtiles + 7) >> 3;
        n = w / nslab; slab = w - n * nslab;   // m-inner (slab varies fastest)
    } else {
        slab = w / nb; n = w - slab * nb;      // n-inner
    }
    int mtile = slab * 8 + xcd;
    if (mtile >= mtiles) return;
    int m0 = mtile * (MBL * 16), n0 = n * (NBL * 16);

    // staging pointers: blob bi = wv + i*4; [0,MBL)=A-blobs, rest B-blobs
    const u16* gp[NST];
    u16* ldst[NST];
    #pragma unroll
    for (int i = 0; i < NST; ++i) {
        int bi = wv + i * 4;
        gp[i] = (bi < MBL)
            ? Ab + ((size_t)(m0 >> 4) + bi) * tstr + lane * 8
            : Bb + ((size_t)(n0 >> 4) + (bi - MBL)) * tstr + lane * 8;
        ldst[i] = smem + bi * 512;
    }

    f32x4 acc[MH2][NW2];
    #pragma unroll
    for (int mi = 0; mi < MH2; ++mi)
        #pragma unroll
        for (int ni = 0; ni < NW2; ++ni) acc[mi][ni] = (f32x4){0.f, 0.f, 0.f, 0.f};

    #pragma unroll
    for (int i = 0; i < NST; ++i) load_lds16(gp[i], ldst[i]);
    __syncthreads();

    for (int tb = 0; tb < KFV; tb += 8) {
        #pragma unroll
        for (int u = 0; u < 8; ++u) {
            int t = tb + u;
            // tb is a multiple of 8 -> parity of t is parity of u: compile-time
            constexpr int par[8] = {0, 1, 0, 1, 0, 1, 0, 1};
            int cur = par[u] * BUFU, nxt = par[(u + 1) & 7] * BUFU;
            if (t + 1 < KFV) {
                #pragma unroll
                for (int i = 0; i < NST; ++i)
                    load_lds16(gp[i] + (size_t)(t + 1) * 512, ldst[i] + nxt);
            }
            bf16x8 a[MH2], bfr[NW2];
            #pragma unroll
            for (int mi = 0; mi < MH2; ++mi)
                a[mi] = *(const bf16x8*)(smem + cur + (wm * MH2 + mi) * 512 + lane * 8);
            #pragma unroll
            for (int ni = 0; ni < NW2; ++ni)
                bfr[ni] = *(const bf16x8*)(smem + cur + (MBL + wn * NW2 + ni) * 512 + lane * 8);
            #pragma unroll
            for (int mi = 0; mi < MH2; ++mi)
                #pragma unroll
                for (int ni = 0; ni < NW2; ++ni)
                    acc[mi][ni] = __builtin_amdgcn_mfma_f32_16x16x32_bf16(
                        a[mi], bfr[ni], acc[mi][ni], 0, 0, 0);
            __syncthreads();
        }
    }

    int m0w = m0 + wm * (MH2 * 16);
    int n0w = n0 + wn * (NW2 * 16);
    float* outf = (float*)outv;
    u16* outblob = (u16*)outv;

    if constexpr ((FLAGS & 8) != 0) {
        // qkv scatter: wave's 64-col span is one (sec, head), uniform per wave
        int sec = n0w / CDIM;
        int h   = (n0w % CDIM) / 64;
        #pragma unroll
        for (int mi = 0; mi < MH2; ++mi) {
            #pragma unroll
            for (int rg = 0; rg < 4; ++rg) {
                int gm = m0w + mi * 16 + fq * 4 + rg;
                if (gm >= M) continue;
                int b   = gm / NTOK;
                int row = gm - b * NTOK;
                int bh  = b * NH + h;
                #pragma unroll
                for (int ni = 0; ni < NW2; ++ni) {
                    int d = ni * 16 + fr;
                    float v = acc[mi][ni][rg] + bias[n0w + d];
                    __hip_bfloat16 hb = __float2bfloat16(v);
                    if (sec == 0) {
                        Qp[(size_t)(bh * QT + (row >> 4)) * 1024 + (d >> 5) * 512 +
                           (((d >> 3) & 3) * 16 + (row & 15)) * 8 + (d & 7)] = *(u16*)&hb;
                    } else if (sec == 1) {
                        Kp[(size_t)(bh * QT + (row >> 4)) * 1024 + (d >> 5) * 512 +
                           (((d >> 3) & 3) * 16 + (row & 15)) * 8 + (d & 7)] = *(u16*)&hb;
                    } else {
                        Vp[((size_t)(bh * 4 + (d >> 4)) * 20 + (row >> 5)) * 512 +
                           (((row >> 3) & 3) * 16 + (d & 15)) * 8 + (row & 7)] = *(u16*)&hb;
                    }
                }
            }
        }
        return;
    }

    if constexpr ((FLAGS & 4) != 0) {
        // blob out: per-wave private LDS staging per m-blob (wave-sync:
        // same wave writes then reads, program order), then linear 16B stores.
        u16* sb = smem + wv * 1024;
        int KfO = Nc >> 5;
        #pragma unroll
        for (int mi = 0; mi < MH2; ++mi) {
            #pragma unroll
            for (int ni = 0; ni < NW2; ++ni)
                #pragma unroll
                for (int rg = 0; rg < 4; ++rg) {
                    int cl = ni * 16 + fr;
                    float v = acc[mi][ni][rg] + bias[n0w + cl];
                    if (FLAGS & 1) v = fast_gelu(v);
                    __hip_bfloat16 hb = __float2bfloat16(v);
                    sb[(cl >> 5) * 512 +
                       (((cl >> 3) & 3) * 16 + fq * 4 + rg) * 8 + (cl & 7)] = *(u16*)&hb;
                }
            u16* dst = outblob + ((size_t)((m0w >> 4) + mi) * KfO + (n0w >> 5)) * 512;
            *(bf16x8*)(dst + lane * 16)     = *(const bf16x8*)(sb + lane * 16);
            *(bf16x8*)(dst + lane * 16 + 8) = *(const bf16x8*)(sb + lane * 16 + 8);
        }
        return;
    }

    #pragma unroll
    for (int mi = 0; mi < MH2; ++mi) {
        #pragma unroll
        for (int rg = 0; rg < 4; ++rg) {
            int gm = m0w + mi * 16 + fq * 4 + rg;
            if (gm >= M) continue;
            #pragma unroll
            for (int ni = 0; ni < NW2; ++ni) {
                int gn = n0w + ni * 16 + fr;
                float v = acc[mi][ni][rg] + bias[gn];
                if (res) v += res[(size_t)gm * Nc + gn];
                outf[(size_t)gm * Nc + gn] = v;
            }
        }
    }
}

// ---------------------------------------------------------------------------
// MFMA flash attention, SWAPPED QK^T (in-register softmax rows) — R9-proven.
// XCD-swizzled grid (xcd owns 24 heads, qc-inner: K/V L2-hot, FETCH at
// compulsory). Double-buffered K/V staging. setprio on MFMA clusters.
// ---------------------------------------------------------------------------
__global__ __launch_bounds__(256) void attn_mfma(
    const u16* __restrict__ Qp, const u16* __restrict__ Kp,
    const u16* __restrict__ Vp, u16* __restrict__ outp)
{
    __shared__ __align__(16) u16 Ks[2][4096];
    __shared__ __align__(16) u16 Vs[2][4096];
    __shared__ __align__(16) u16 Ps[4 * 16 * 72];

    int fid = blockIdx.x;
    int xcd = fid & 7, w = fid >> 3;       // w in [0, 240)
    int bhl = w / 10, qc = w - bhl * 10;   // qc-inner
    int bh = xcd * 24 + bhl;
    int b = bh / NH, h = bh % NH;
    int t = threadIdx.x, lane = t & 63, wv = t >> 6;
    int fr = lane & 15, fq = lane >> 4;

    int mt = qc * 4 + wv;
    const u16* qbase = Qp + (size_t)(bh * QT + mt) * 1024 + lane * 8;
    bf16x8 qf0 = *(const bf16x8*)(qbase);
    bf16x8 qf1 = *(const bf16x8*)(qbase + 512);

    const u16* kg = Kp + (size_t)bh * (QT * 1024) + wv * 1024 + lane * 8;
    const u16* vg = Vp + ((size_t)(bh * 4 + wv) * 20) * 512 + lane * 8;
    u16* psw = Ps + wv * (16 * 72);

#define STAGE(buf, kt) do {                                        \
    load_lds16(kg + (kt) * 4096,       &Ks[buf][wv * 1024]);       \
    load_lds16(kg + (kt) * 4096 + 512, &Ks[buf][wv * 1024 + 512]); \
    load_lds16(vg + (kt) * 1024,       &Vs[buf][wv * 1024]);       \
    load_lds16(vg + (kt) * 1024 + 512, &Vs[buf][wv * 1024 + 512]); \
} while (0)

    f32x4 o[4];
    #pragma unroll
    for (int i = 0; i < 4; ++i) o[i] = (f32x4){0.f, 0.f, 0.f, 0.f};
    float m_r = -1e30f, l_r = 0.f;   // per-lane state for q = fr

    STAGE(0, 0);
    __syncthreads();

    for (int kt = 0; kt < 10; ++kt) {
        int cur = kt & 1;
        if (kt + 1 < 10) STAGE(cur ^ 1, kt + 1);

        f32x4 sc[4];
        __builtin_amdgcn_s_setprio(1);
        #pragma unroll
        for (int nt = 0; nt < 4; ++nt) {
            sc[nt] = (f32x4){0.f, 0.f, 0.f, 0.f};
            bf16x8 kf0 = *(const bf16x8*)(&Ks[cur][(nt * 2 + 0) * 512] + lane * 8);
            bf16x8 kf1 = *(const bf16x8*)(&Ks[cur][(nt * 2 + 1) * 512] + lane * 8);
            // SWAPPED: A = K (keys = rows), B = Q (q = cols) -> S^T
            sc[nt] = __builtin_amdgcn_mfma_f32_16x16x32_bf16(kf0, qf0, sc[nt], 0, 0, 0);
            sc[nt] = __builtin_amdgcn_mfma_f32_16x16x32_bf16(kf1, qf1, sc[nt], 0, 0, 0);
        }
        __builtin_amdgcn_s_setprio(0);

        int j0 = kt * 64;
        float p[4][4];
        #pragma unroll
        for (int nt = 0; nt < 4; ++nt)
            #pragma unroll
            for (int rg = 0; rg < 4; ++rg) {
                int k = j0 + nt * 16 + fq * 4 + rg;
                p[nt][rg] = (k < NTOK) ? sc[nt][rg] * 0.125f : -1e30f;
            }
        // in-register max tree over the lane's 16 scores
        float mx01 = fmaxf(fmaxf(p[0][0], p[0][1]), fmaxf(p[0][2], p[0][3]));
        float mx23 = fmaxf(fmaxf(p[1][0], p[1][1]), fmaxf(p[1][2], p[1][3]));
        float mx45 = fmaxf(fmaxf(p[2][0], p[2][1]), fmaxf(p[2][2], p[2][3]));
        float mx67 = fmaxf(fmaxf(p[3][0], p[3][1]), fmaxf(p[3][2], p[3][3]));
        float pm = fmaxf(fmaxf(mx01, mx23), fmaxf(mx45, mx67));
        // combine the 4 fq replicas of this q (lanes fr, fr+16, fr+32, fr+48)
        pm = fmaxf(pm, __shfl_xor(pm, 16));
        pm = fmaxf(pm, __shfl_xor(pm, 32));

        float mn = fmaxf(m_r, pm);
        float alpha = __expf(m_r - mn);
        m_r = mn;

        float rs = 0.f;
        #pragma unroll
        for (int nt = 0; nt < 4; ++nt)
            #pragma unroll
            for (int rg = 0; rg < 4; ++rg) {
                float pv = __expf(p[nt][rg] - mn);
                p[nt][rg] = pv;
                rs += pv;
            }
        rs += __shfl_xor(rs, 16);
        rs += __shfl_xor(rs, 32);
        l_r = l_r * alpha + rs;

        // P -> psw: lane owns row q=fr, 4 consecutive keys per nt -> b64 store
        #pragma unroll
        for (int nt = 0; nt < 4; ++nt) {
            __hip_bfloat16 c0 = __float2bfloat16(p[nt][0]);
            __hip_bfloat16 c1 = __float2bfloat16(p[nt][1]);
            __hip_bfloat16 c2 = __float2bfloat16(p[nt][2]);
            __hip_bfloat16 c3 = __float2bfloat16(p[nt][3]);
            ushort4 pk = make_ushort4(*(u16*)&c0, *(u16*)&c1, *(u16*)&c2, *(u16*)&c3);
            *(ushort4*)(psw + fr * 72 + nt * 16 + fq * 4) = pk;
        }

        // rescale O: its rows are q = fq*4+rg -> fetch those lanes' alpha
        #pragma unroll
        for (int rg = 0; rg < 4; ++rg) {
            float al = __shfl(alpha, fq * 4 + rg);
            #pragma unroll
            for (int dt = 0; dt < 4; ++dt)
                o[dt][rg] *= al;
        }

        bf16x8 pf0 = *(const bf16x8*)(psw + fr * 72 + fq * 8);
        bf16x8 pf1 = *(const bf16x8*)(psw + fr * 72 + 32 + fq * 8);
        __builtin_amdgcn_s_setprio(1);
        #pragma unroll
        for (int dt = 0; dt < 4; ++dt) {
            bf16x8 bv0 = *(const bf16x8*)(&Vs[cur][(dt * 2 + 0) * 512] + lane * 8);
            bf16x8 bv1 = *(const bf16x8*)(&Vs[cur][(dt * 2 + 1) * 512] + lane * 8);
            o[dt] = __builtin_amdgcn_mfma_f32_16x16x32_bf16(pf0, bv0, o[dt], 0, 0, 0);
            o[dt] = __builtin_amdgcn_mfma_f32_16x16x32_bf16(pf1, bv1, o[dt], 0, 0, 0);
        }
        __builtin_amdgcn_s_setprio(0);
        __syncthreads();   // drains this step's prefetch + read-sync of cur
    }
#undef STAGE

    #pragma unroll
    for (int rg = 0; rg < 4; ++rg) {
        int row = qc * 64 + wv * 16 + fq * 4 + rg;
        if (row < NTOK) {
            float lq = __shfl(l_r, fq * 4 + rg);   // l for O's q-row
            float rl = 1.0f / lq;
            int grow = b * NTOK + row;
            #pragma unroll
            for (int dt = 0; dt < 4; ++dt) {
                __hip_bfloat16 hb = __float2bfloat16(o[dt][rg] * rl);
                outp[blobA(grow, h * 64 + dt * 16 + fr, KF_C)] = *(u16*)&hb;
            }
        }
    }
}

// ---------------------------------------------------------------------------
static inline int tg_grid(int nb, int mt) { return 8 * nb * ((mt + 7) / 8); }

extern "C" void kernel_launch(void* const* d_in, const int* in_sizes, int n_in,
                              void* d_out, int out_size, void* d_ws, size_t ws_size,
                              hipStream_t stream)
{
    const float* x      = (const float*)d_in[0];
    const float* ln1_g  = (const float*)d_in[1];
    const float* ln1_b  = (const float*)d_in[2];
    const float* w_qkv  = (const float*)d_in[3];
    const float* b_qkv  = (const float*)d_in[4];
    const float* w_proj = (const float*)d_in[5];
    const float* b_proj = (const float*)d_in[6];
    const float* ln2_g  = (const float*)d_in[7];
    const float* ln2_b  = (const float*)d_in[8];
    const float* w_fc1  = (const float*)d_in[9];
    const float* b_fc1  = (const float*)d_in[10];
    const float* w_fc2  = (const float*)d_in[11];
    const float* b_fc2  = (const float*)d_in[12];
    float* out = (float*)d_out;

    char* w = (char*)d_ws;
    u16* Bqkv = (u16*)w; w += (size_t)3*CDIM*CDIM*2;
    u16* Bproj= (u16*)w; w += (size_t)CDIM*CDIM*2;
    u16* Bfc1 = (u16*)w; w += (size_t)HID*CDIM*2;
    u16* Bfc2 = (u16*)w; w += (size_t)CDIM*HID*2;
    u16* hA   = (u16*)w; w += (size_t)RPAD*CDIM*2;   // blob activations (768)
    u16* h3A  = (u16*)w; w += (size_t)RPAD*HID*2;    // blob activations (3072)
    u16* Qp   = (u16*)w; w += (size_t)BH*QT*1024*2;
    u16* Kp   = (u16*)w; w += (size_t)BH*QT*1024*2;
    u16* Vp   = (u16*)w; w += (size_t)BH*4*20*512*2;

    int mt64 = (RTOT + 63) / 64;     // 145 m-tiles for 64-row blocks

    // 0. weights -> fragment blobs
    wconvert_blob<<<dim3(3*CDIM/256, CDIM/8), 256, 0, stream>>>(w_qkv,  Bqkv, CDIM, 3*CDIM);
    wconvert_blob<<<dim3(CDIM/256,   CDIM/8), 256, 0, stream>>>(w_proj, Bproj, CDIM, CDIM);
    wconvert_blob<<<dim3(HID/256,    CDIM/8), 256, 0, stream>>>(w_fc1,  Bfc1, CDIM, HID);
    wconvert_blob<<<dim3(CDIM/256,   HID/8),  256, 0, stream>>>(w_fc2,  Bfc2, HID, CDIM);

    // 1. hA = LN1(x)  (blob)
    ln_kernel<<<RTOT, 256, 0, stream>>>(x, ln1_g, ln1_b, hA);
    // 2. qkv GEMM -> Q/K/V blobs  (64x128, BK=32, m-inner, Kf=24)
    tile_gemm<4, 8, 8 | 16, 24><<<tg_grid(3*CDIM/128, mt64), 256, 0, stream>>>(
        hA, Bqkv, b_qkv, nullptr, nullptr, Qp, Kp, Vp,
        RTOT, 3*CDIM, 3*CDIM/128, mt64);
    // 3. attention -> hA (blob)
    attn_mfma<<<8 * 24 * 10, 256, 0, stream>>>(Qp, Kp, Vp, hA);
    // 4. x1 = x + hA @ Bproj^T + b_proj -> d_out (fp32; n-inner, Kf=24)
    tile_gemm<4, 8, 0, 24><<<tg_grid(CDIM/128, mt64), 256, 0, stream>>>(
        hA, Bproj, b_proj, x, out, nullptr, nullptr, nullptr,
        RTOT, CDIM, CDIM/128, mt64);
    // 5. hA = LN2(x1)  (blob)
    ln_kernel<<<RTOT, 256, 0, stream>>>(out, ln2_g, ln2_b, hA);
    // 6. h3A = gelu(hA @ Bfc1^T + b_fc1)  (blob out; m-inner, Kf=24)
    tile_gemm<4, 8, 5 | 16, 24><<<tg_grid(HID/128, mt64), 256, 0, stream>>>(
        hA, Bfc1, b_fc1, nullptr, h3A, nullptr, nullptr, nullptr,
        RTOT, HID, HID/128, mt64);
    // 7. out = x1 + h3A @ Bfc2^T + b_fc2  (fp32; n-inner, Kf=96)
    tile_gemm<4, 8, 0, 96><<<tg_grid(CDIM/128, mt64), 256, 0, stream>>>(
        h3A, Bfc2, b_fc2, out, out, nullptr, nullptr, nullptr,
        RTOT, CDIM, CDIM/128, mt64);
}